// Round 5
// baseline (278.239 us; speedup 1.0000x reference)
//
#include <hip/hip_runtime.h>
#include <hip/hip_bf16.h>

#define SIZE 1024
#define NH 16
#define HD 64
#define BB 2
#define SS 2048
#define MROWS (BB * SS)  // 4096
#define QT 256           // attn q-tile (64 rows per wave)
#define NQT (SS / QT)    // 8 q-tiles per (b,h)
#define NKT ((SS / 2) / 64)  // 16 k-tiles per S-half

using bf16 = __hip_bfloat16;
using frag16 = __attribute__((ext_vector_type(8))) short;   // 8 bf16 (4 VGPRs)
using f32x4 = __attribute__((ext_vector_type(4))) float;    // 4 fp32 acc
typedef unsigned int u32;

// async global->LDS, 16B per lane; lds dest = wave-uniform base + lane*16 (m97/m104)
__device__ __forceinline__ void glds16(const bf16* g, bf16* l) {
    __builtin_amdgcn_global_load_lds(
        (const __attribute__((address_space(1))) u32*)g,
        (__attribute__((address_space(3))) u32*)l, 16, 0, 0);
}

__device__ __forceinline__ void cvt_store8(bf16* dst, const float* src) {
    float4 a = *(const float4*)src;
    float4 b = *(const float4*)(src + 4);
    bf16 t[8];
    t[0] = __float2bfloat16(a.x); t[1] = __float2bfloat16(a.y);
    t[2] = __float2bfloat16(a.z); t[3] = __float2bfloat16(a.w);
    t[4] = __float2bfloat16(b.x); t[5] = __float2bfloat16(b.y);
    t[6] = __float2bfloat16(b.z); t[7] = __float2bfloat16(b.w);
    *(uint4*)dst = *(const uint4*)t;
}

// ---------------------------------------------------------------------------
// Weights-only fp32 -> bf16 cast (activations now cast in-flight inside qkv):
// 24 MB pass instead of 96 MB.
// ---------------------------------------------------------------------------
__global__ __launch_bounds__(256) void cast_w_kernel(
    const float* __restrict__ Wq, const float* __restrict__ Wk,
    const float* __restrict__ Wv, const float* __restrict__ Wo,
    bf16* __restrict__ Wb)
{
    const int z = blockIdx.y;
    const float* s = (z == 0) ? Wq : (z == 1) ? Wk : (z == 2) ? Wv : Wo;
    const int i = (blockIdx.x * 256 + threadIdx.x) * 8;   // grid.x = 512 -> 1M elems
    cvt_store8(Wb + (size_t)z * SIZE * SIZE + i, s + i);
}

// ---------------------------------------------------------------------------
// qkv GEMM, reg-staged fp32 A + glds16 bf16 B, DOUBLE-BUFFERED, BK=32,
// ONE barrier per K-step (R3-attn-proven pipeline):
//   issue A-loads(kt+1) + glds16 B(kt+1 -> buf^1)  BEFORE compute(buf),
//   commit A regs -> As[buf^1] AFTER compute, then one __syncthreads().
// A tile padded [128][36] to spread reg-staged ds_write banks; B stays
// linear [128][32] (glds16 requires it; its frag-read pattern is the proven
// balanced one). Kills the activation cast pass (72 MB round-trip).
// vt_mode: epilogue transposes via LDS and writes vt[b][h][d][s] coalesced.
// ---------------------------------------------------------------------------
__device__ __forceinline__ void gemm_body(
    const float* __restrict__ X, const bf16* __restrict__ W,
    const float* __restrict__ bias, bf16* __restrict__ Y, float scale, bool vt_mode)
{
    __shared__ __align__(16) bf16 As[2][128][36];   // 9 KB x2, reg-staged (padded)
    __shared__ __align__(16) bf16 Bs[2][128][32];   // 8 KB x2, glds16 (linear)

    const int tid = threadIdx.x;
    const int wave = tid >> 6;
    const int lane = tid & 63;
    const int lane15 = lane & 15;
    const int quad = lane >> 4;
    const int bm = blockIdx.y * 128;
    const int bn = blockIdx.x * 128;
    const int wm = (wave & 1) * 64;
    const int wn = (wave >> 1) * 64;

    f32x4 acc[4][4];
#pragma unroll
    for (int i = 0; i < 4; i++)
#pragma unroll
        for (int j = 0; j < 4; j++)
            acc[i][j] = (f32x4){0.f, 0.f, 0.f, 0.f};

    const int srow = lane >> 2;        // 0..15 within 16-row chunk (B staging)
    const int scol = (lane & 3) * 8;   // 0/8/16/24
    const int arow = tid >> 1;         // 0..127 (A staging: 2 threads/row)
    const int acolg = (tid & 1) * 16;  // 0 or 16
    const float* xrow = X + (size_t)(bm + arow) * SIZE + acolg;

    float4 f0, f1, f2, f3;             // A tile in flight (16 fp32)

#define ISSUE_A(KT)                                                        \
    {                                                                      \
        const float* xp = xrow + (KT) * 32;                                \
        f0 = *(const float4*)(xp);      f1 = *(const float4*)(xp + 4);     \
        f2 = *(const float4*)(xp + 8);  f3 = *(const float4*)(xp + 12);    \
    }
#define COMMIT_A(BUF)                                                      \
    {                                                                      \
        bf16 t[16];                                                        \
        t[0] = __float2bfloat16(f0.x);  t[1] = __float2bfloat16(f0.y);     \
        t[2] = __float2bfloat16(f0.z);  t[3] = __float2bfloat16(f0.w);     \
        t[4] = __float2bfloat16(f1.x);  t[5] = __float2bfloat16(f1.y);     \
        t[6] = __float2bfloat16(f1.z);  t[7] = __float2bfloat16(f1.w);     \
        t[8] = __float2bfloat16(f2.x);  t[9] = __float2bfloat16(f2.y);     \
        t[10] = __float2bfloat16(f2.z); t[11] = __float2bfloat16(f2.w);    \
        t[12] = __float2bfloat16(f3.x); t[13] = __float2bfloat16(f3.y);    \
        t[14] = __float2bfloat16(f3.z); t[15] = __float2bfloat16(f3.w);    \
        *(uint4*)&As[BUF][arow][acolg]     = *(const uint4*)t;             \
        *(uint4*)&As[BUF][arow][acolg + 8] = *(const uint4*)(t + 8);       \
    }
#define GLDS_B(KT, BUF)                                                    \
    {                                                                      \
        _Pragma("unroll")                                                  \
        for (int n = 0; n < 2; n++) {                                      \
            const int c = wave * 2 + n;                                    \
            glds16(W + (size_t)(bn + c * 16 + srow) * SIZE + (KT) * 32 + scol, \
                   &Bs[BUF][0][0] + c * 512);                              \
        }                                                                  \
    }

    // prologue: tile 0 (latency exposed once)
    ISSUE_A(0); COMMIT_A(0); GLDS_B(0, 0);
    __syncthreads();

    for (int kt = 0; kt < SIZE / 32; kt++) {
        const int buf = kt & 1;
        if (kt + 1 < SIZE / 32) { ISSUE_A(kt + 1); GLDS_B(kt + 1, buf ^ 1); }
        __builtin_amdgcn_sched_barrier(0);        // pin prefetch before compute

        frag16 a[4], b[4];
#pragma unroll
        for (int mi = 0; mi < 4; mi++)
            a[mi] = *(const frag16*)&As[buf][wm + mi * 16 + lane15][quad * 8];
#pragma unroll
        for (int ni = 0; ni < 4; ni++)
            b[ni] = *(const frag16*)&Bs[buf][wn + ni * 16 + lane15][quad * 8];
#pragma unroll
        for (int mi = 0; mi < 4; mi++)
#pragma unroll
            for (int ni = 0; ni < 4; ni++)
                acc[mi][ni] = __builtin_amdgcn_mfma_f32_16x16x32_bf16(
                    a[mi], b[ni], acc[mi][ni], 0, 0, 0);

        if (kt + 1 < SIZE / 32) {
            COMMIT_A(buf ^ 1);                    // A-loads landed by now
            __syncthreads();                      // drains glds16 too (vmcnt0)
        }
    }
#undef ISSUE_A
#undef COMMIT_A
#undef GLDS_B

    if (!vt_mode) {
        // C/D layout col=lane&15, row=quad*4+reg (m89/m91)
#pragma unroll
        for (int ni = 0; ni < 4; ni++) {
            const int col = bn + wn + ni * 16 + lane15;
            const float bv = bias[col];
#pragma unroll
            for (int mi = 0; mi < 4; mi++) {
                const int row = bm + wm + mi * 16 + quad * 4;
#pragma unroll
                for (int r = 0; r < 4; r++)
                    Y[(size_t)(row + r) * SIZE + col] =
                        __float2bfloat16((acc[mi][ni][r] + bv) * scale);
            }
        }
    } else {
        // transpose epilogue -> vt[b][h][d][s], coalesced 16B stores
        bf16* tr = &As[0][0][0];           // [64][136] = 8704 elems, fits in As
        const int bloc = bm >> 11;
        const int s0g = bm & (SS - 1);
#pragma unroll
        for (int p = 0; p < 2; p++) {
            __syncthreads();
            if ((wave >> 1) == p) {
#pragma unroll
                for (int ni = 0; ni < 4; ni++) {
                    const int colp = ni * 16 + lane15;
                    const float bv = bias[bn + p * 64 + colp];
#pragma unroll
                    for (int mi = 0; mi < 4; mi++) {
                        const int row = wm + mi * 16 + quad * 4;
#pragma unroll
                        for (int r = 0; r < 4; r++)
                            tr[colp * 136 + row + r] =
                                __float2bfloat16(acc[mi][ni][r] + bv);
                    }
                }
            }
            __syncthreads();
            const int colp = tid >> 2;
            const int gcol = bn + p * 64 + colp;
            const int hh = gcol >> 6, dd = gcol & (HD - 1);
            bf16* dst = (bf16*)Y + ((size_t)(bloc * NH + hh) * HD + dd) * SS
                        + s0g + (tid & 3) * 32;
            const bf16* src = tr + colp * 136 + (tid & 3) * 32;
#pragma unroll
            for (int j = 0; j < 4; j++)
                *(uint4*)(dst + j * 8) = *(const uint4*)(src + j * 8);
        }
    }
}

__global__ __launch_bounds__(256) void qkv_proj_kernel(
    const float* __restrict__ q, const float* __restrict__ k, const float* __restrict__ v,
    const bf16* __restrict__ Wb,
    const float* __restrict__ bq, const float* __restrict__ bk, const float* __restrict__ bv,
    bf16* __restrict__ qh, bf16* __restrict__ kh, bf16* __restrict__ vt)
{
    const float* X; const bf16* W; const float* bi; bf16* Y; float sc; bool vm;
    if (blockIdx.z == 0)      { X = q; W = Wb;                   bi = bq; Y = qh; sc = 0.125f; vm = false; }
    else if (blockIdx.z == 1) { X = k; W = Wb + SIZE * SIZE;     bi = bk; Y = kh; sc = 1.0f;   vm = false; }
    else                      { X = v; W = Wb + 2 * SIZE * SIZE; bi = bv; Y = vt; sc = 1.0f;   vm = true;  }
    gemm_body(X, W, bi, Y, sc, vm);
}

// ---------------------------------------------------------------------------
// Flash attention, split-S, QT=256 (64 q-rows/wave), DOUBLE-BUFFERED K/V.
// (R3-proven: 66.6us. Frozen.)
// ---------------------------------------------------------------------------
__global__ __launch_bounds__(256) void attn_kernel(
    const bf16* __restrict__ qh, const bf16* __restrict__ kh,
    const bf16* __restrict__ vt, bf16* __restrict__ po, float* __restrict__ pl)
{
    __shared__ __align__(16) bf16 Ks[2][64][72];
    __shared__ __align__(16) bf16 Vs[2][64][72];
    __shared__ __align__(16) bf16 Ps[4][64][72];

    const int tid = threadIdx.x;
    const int wave = tid >> 6;
    const int lane = tid & 63;
    const int lane15 = lane & 15;
    const int quad = lane >> 4;

    const int b = blockIdx.z, h = blockIdx.y;
    const int qt = blockIdx.x >> 1;
    const int sh = blockIdx.x & 1;
    const int q0 = qt * QT;

    const size_t baseq = (size_t)b * SS * SIZE + (size_t)h * HD;
    const size_t basev = (size_t)(b * NH + h) * HD * SS;
    const float LOG2E = 1.44269504088896340736f;
    const float OFF = 12.0f * LOG2E;

    frag16 aq[4][2];
#pragma unroll
    for (int m = 0; m < 4; m++) {
        const int qrow = q0 + wave * 64 + m * 16 + lane15;
        const bf16* qp = qh + baseq + (size_t)qrow * SIZE + quad * 8;
        aq[m][0] = *(const frag16*)(qp);
        aq[m][1] = *(const frag16*)(qp + 32);
    }

    frag16 bones;
#pragma unroll
    for (int e = 0; e < 8; e++) bones[e] = (short)0x3F80;   // bf16 1.0

    f32x4 ofrag[4][4], l_frag[4];
#pragma unroll
    for (int m = 0; m < 4; m++) {
        l_frag[m] = (f32x4){0.f, 0.f, 0.f, 0.f};
#pragma unroll
        for (int dt = 0; dt < 4; dt++) ofrag[m][dt] = (f32x4){0.f, 0.f, 0.f, 0.f};
    }

    const int sr = tid >> 3;          // 0..31
    const int sc = (tid & 7) * 8;

    // staging registers (tile in flight)
    uint4 rk0, rk1, rv0, rv1;

#define ISSUE(KT)                                                              \
    {                                                                          \
        const int s0_ = sh * (SS / 2) + (KT) * 64;                             \
        rk0 = *(const uint4*)(kh + baseq + (size_t)(s0_ + sr) * SIZE + sc);    \
        rk1 = *(const uint4*)(kh + baseq + (size_t)(s0_ + sr + 32) * SIZE + sc);\
        rv0 = *(const uint4*)(vt + basev + (size_t)sr * SS + s0_ + sc);        \
        rv1 = *(const uint4*)(vt + basev + (size_t)(sr + 32) * SS + s0_ + sc); \
    }
#define COMMIT(BUF)                                                            \
    {                                                                          \
        *(uint4*)&Ks[BUF][sr][sc] = rk0; *(uint4*)&Ks[BUF][sr + 32][sc] = rk1; \
        *(uint4*)&Vs[BUF][sr][sc] = rv0; *(uint4*)&Vs[BUF][sr + 32][sc] = rv1; \
    }

    // prologue: tile 0 (latency exposed once)
    ISSUE(0); COMMIT(0);
    __syncthreads();

    for (int kt = 0; kt < NKT; kt++) {
        const int buf = kt & 1;
        if (kt + 1 < NKT) ISSUE(kt + 1);          // prefetch in flight
        __builtin_amdgcn_sched_barrier(0);        // pin loads before compute

        // ---- S^T = K Q^T, softmax, packed P store ----
        frag16 kf[4][2];
#pragma unroll
        for (int nt = 0; nt < 4; nt++) {
            kf[nt][0] = *(const frag16*)&Ks[buf][nt * 16 + lane15][quad * 8];
            kf[nt][1] = *(const frag16*)&Ks[buf][nt * 16 + lane15][32 + quad * 8];
        }
#pragma unroll
        for (int m = 0; m < 4; m++) {
#pragma unroll
            for (int nt = 0; nt < 4; nt++) {
                f32x4 c = (f32x4){0.f, 0.f, 0.f, 0.f};
                c = __builtin_amdgcn_mfma_f32_16x16x32_bf16(kf[nt][0], aq[m][0], c, 0, 0, 0);
                c = __builtin_amdgcn_mfma_f32_16x16x32_bf16(kf[nt][1], aq[m][1], c, 0, 0, 0);
                // c[r] = S[q = m*16+lane15][key = nt*16 + quad*4 + r]
                bf16 p4[4];
#pragma unroll
                for (int r = 0; r < 4; r++)
                    p4[r] = __float2bfloat16(exp2f(c[r] * LOG2E - OFF));
                *(uint2*)&Ps[wave][m * 16 + lane15][nt * 16 + quad * 4] = *(const uint2*)p4;
            }
        }
        __builtin_amdgcn_wave_barrier();   // Ps wave-private; DS in-order per wave

        frag16 ap[4][2];
#pragma unroll
        for (int m = 0; m < 4; m++)
#pragma unroll
            for (int c2 = 0; c2 < 2; c2++)
                ap[m][c2] = *(const frag16*)&Ps[wave][m * 16 + lane15][c2 * 32 + quad * 8];

        __builtin_amdgcn_s_setprio(1);
        // ---- l += P @ 1 ----
#pragma unroll
        for (int m = 0; m < 4; m++)
#pragma unroll
            for (int c2 = 0; c2 < 2; c2++)
                l_frag[m] = __builtin_amdgcn_mfma_f32_16x16x32_bf16(
                    ap[m][c2], bones, l_frag[m], 0, 0, 0);

        // ---- O += P V ----
#pragma unroll
        for (int dt = 0; dt < 4; dt++) {
            frag16 bv0 = *(const frag16*)&Vs[buf][dt * 16 + lane15][quad * 8];
            frag16 bv1 = *(const frag16*)&Vs[buf][dt * 16 + lane15][32 + quad * 8];
#pragma unroll
            for (int m = 0; m < 4; m++) {
                ofrag[m][dt] = __builtin_amdgcn_mfma_f32_16x16x32_bf16(ap[m][0], bv0, ofrag[m][dt], 0, 0, 0);
                ofrag[m][dt] = __builtin_amdgcn_mfma_f32_16x16x32_bf16(ap[m][1], bv1, ofrag[m][dt], 0, 0, 0);
            }
        }
        __builtin_amdgcn_s_setprio(0);

        if (kt + 1 < NKT) {
            COMMIT(buf ^ 1);                      // prefetch landed by now
            __syncthreads();
        }
    }
#undef ISSUE
#undef COMMIT

    // ---- partial outputs (un-normalized O + row sums) ----
    const int pb = ((b * NH + h) * NQT + qt) * 2 + sh;
    if (lane15 == 0) {
        float* plp = pl + (size_t)pb * QT;
#pragma unroll
        for (int m = 0; m < 4; m++)
#pragma unroll
            for (int r = 0; r < 4; r++)
                plp[wave * 64 + m * 16 + quad * 4 + r] = l_frag[m][r];
    }
    bf16* pop = po + (size_t)pb * QT * HD;
#pragma unroll
    for (int m = 0; m < 4; m++)
#pragma unroll
        for (int dt = 0; dt < 4; dt++)
#pragma unroll
            for (int r = 0; r < 4; r++)
                pop[(size_t)(wave * 64 + m * 16 + quad * 4 + r) * HD + dt * 16 + lane15] =
                    __float2bfloat16(ofrag[m][dt][r]);
}

// ---------------------------------------------------------------------------
// Output projection with FUSED combine (R4 structure, frozen): A-tile =
// (po0+po1)*inv in registers, B = Wo via glds16. BM=64 x BN=128, BK=64.
// ---------------------------------------------------------------------------
__global__ __launch_bounds__(256) void out_proj_kernel(
    const bf16* __restrict__ po, const float* __restrict__ pl,
    const bf16* __restrict__ Wob, const float* __restrict__ bo,
    float* __restrict__ out)
{
    __shared__ __align__(16) bf16 As[2 * 64 * 32];    // [2 planes][64][32]
    __shared__ __align__(16) bf16 Bs[2 * 128 * 32];   // [2 planes][128][32]

    const int tid = threadIdx.x;
    const int wave = tid >> 6;
    const int lane = tid & 63;
    const int lane15 = lane & 15;
    const int quad = lane >> 4;
    const int bm = blockIdx.y * 64;
    const int bn = blockIdx.x * 128;
    const int wn = wave * 32;

    f32x4 acc[4][2];
#pragma unroll
    for (int i = 0; i < 4; i++)
#pragma unroll
        for (int j = 0; j < 2; j++)
            acc[i][j] = (f32x4){0.f, 0.f, 0.f, 0.f};

    const int srow = lane >> 2;        // 0..15
    const int scol = (lane & 3) * 8;

    const int arow = tid >> 2;
    const int acol = (tid & 3) * 8;
    const int gr = bm + arow;                 // global ctx row
    const int bIdx = gr >> 11;                // batch
    const int s = gr & (SS - 1);
    const int qt8 = s >> 8;                   // 256-row attn tile
    const int sq = s & (QT - 1);

    uint4 p0a, p1a, p0b, p1b;                 // {half0,half1} x {plane0,plane1}
    float l0, l1;

#define ALOAD(KT)                                                                 \
    {                                                                             \
        const int pb0_ = ((bIdx * NH + (KT)) * NQT + qt8) * 2;                    \
        const bf16* q0_ = po + (size_t)pb0_ * QT * HD + sq * HD;                  \
        const bf16* q1_ = po + (size_t)(pb0_ + 1) * QT * HD + sq * HD;            \
        p0a = *(const uint4*)(q0_ + acol);                                        \
        p0b = *(const uint4*)(q0_ + 32 + acol);                                   \
        p1a = *(const uint4*)(q1_ + acol);                                        \
        p1b = *(const uint4*)(q1_ + 32 + acol);                                   \
        l0 = pl[(size_t)pb0_ * QT + sq];                                          \
        l1 = pl[(size_t)(pb0_ + 1) * QT + sq];                                    \
    }

    ALOAD(0);

    for (int kt = 0; kt < NH; kt++) {         // 16 iterations, k0 = kt*64, h = kt
        __syncthreads();                      // prev readers done
        // ---- commit A (fused combine) ----
        {
            const float inv = 1.0f / fmaxf(l0 + l1, 1e-30f);
            const bf16* x0 = (const bf16*)&p0a; const bf16* y0 = (const bf16*)&p1a;
            const bf16* x1 = (const bf16*)&p0b; const bf16* y1 = (const bf16*)&p1b;
            bf16 o0[8], o1[8];
#pragma unroll
            for (int e = 0; e < 8; e++) {
                o0[e] = __float2bfloat16((__bfloat162float(x0[e]) + __bfloat162float(y0[e])) * inv);
                o1[e] = __float2bfloat16((__bfloat162float(x1[e]) + __bfloat162float(y1[e])) * inv);
            }
            *(uint4*)(As + 0 * 2048 + arow * 32 + acol) = *(const uint4*)o0;
            *(uint4*)(As + 1 * 2048 + arow * 32 + acol) = *(const uint4*)o1;
        }
        // ---- B glds16 staging ----
#pragma unroll
        for (int n = 0; n < 4; n++) {
            const int c = wave * 4 + n;
            const int plane = c >> 3;
            const int cc = c & 7;
            glds16(Wob + (size_t)(bn + cc * 16 + srow) * SIZE + kt * 64 + plane * 32 + scol,
                   Bs + c * 512);
        }
        __syncthreads();                      // drain ds_write + glds16

        if (kt + 1 < NH) ALOAD(kt + 1);       // prefetch flows under MFMAs

#pragma unroll
        for (int kk = 0; kk < 2; kk++) {
            frag16 a[4], b[2];
#pragma unroll
            for (int mi = 0; mi < 4; mi++)
                a[mi] = *(const frag16*)(As + kk * 2048 + (mi * 16 + lane15) * 32 + quad * 8);
#pragma unroll
            for (int ni = 0; ni < 2; ni++)
                b[ni] = *(const frag16*)(Bs + kk * 4096 + (wn + ni * 16 + lane15) * 32 + quad * 8);
#pragma unroll
            for (int mi = 0; mi < 4; mi++)
#pragma unroll
                for (int ni = 0; ni < 2; ni++)
                    acc[mi][ni] = __builtin_amdgcn_mfma_f32_16x16x32_bf16(
                        a[mi], b[ni], acc[mi][ni], 0, 0, 0);
        }
    }
#undef ALOAD

#pragma unroll
    for (int ni = 0; ni < 2; ni++) {
        const int col = bn + wn + ni * 16 + lane15;
        const float bv = bo[col];
#pragma unroll
        for (int mi = 0; mi < 4; mi++) {
            const int row = bm + mi * 16 + quad * 4;
#pragma unroll
            for (int r = 0; r < 4; r++)
                out[(size_t)(row + r) * SIZE + col] = acc[mi][ni][r] + bv;
        }
    }
}

extern "C" void kernel_launch(void* const* d_in, const int* in_sizes, int n_in,
                              void* d_out, int out_size, void* d_ws, size_t ws_size,
                              hipStream_t stream) {
    const float* q  = (const float*)d_in[0];
    const float* k  = (const float*)d_in[1];
    const float* v  = (const float*)d_in[2];
    const float* Wq = (const float*)d_in[3];
    const float* bq = (const float*)d_in[4];
    const float* Wk = (const float*)d_in[5];
    const float* bk = (const float*)d_in[6];
    const float* Wv = (const float*)d_in[7];
    const float* bv = (const float*)d_in[8];
    const float* Wo = (const float*)d_in[9];
    const float* bo = (const float*)d_in[10];
    float* out = (float*)d_out;

    // ws (bf16): Wb[4M] | qh[4M] | kh[4M] | vt[4M] | po[8.39M] | pl(f32 512KB)
    bf16* Wb = (bf16*)d_ws;
    bf16* qh = Wb + (size_t)4 * SIZE * SIZE;
    bf16* kh = qh + (size_t)MROWS * SIZE;
    bf16* vt = kh + (size_t)MROWS * SIZE;
    bf16* po = vt + (size_t)MROWS * SIZE;
    float* pl = (float*)(po + (size_t)BB * NH * NQT * 2 * QT * HD);

    cast_w_kernel<<<dim3(SIZE * SIZE / 2048, 4, 1), 256, 0, stream>>>(
        Wq, Wk, Wv, Wo, Wb);
    qkv_proj_kernel<<<dim3(SIZE / 128, MROWS / 128, 3), 256, 0, stream>>>(
        q, k, v, Wb, bq, bk, bv, qh, kh, vt);
    attn_kernel<<<dim3(NQT * 2, NH, BB), 256, 0, stream>>>(qh, kh, vt, po, pl);
    out_proj_kernel<<<dim3(SIZE / 128, MROWS / 64, 1), 256, 0, stream>>>(
        po, pl, Wb + (size_t)3 * SIZE * SIZE, bo, out);
}

// Round 6
// 253.604 us; speedup vs baseline: 1.0971x; 1.0971x over previous
//
#include <hip/hip_runtime.h>
#include <hip/hip_bf16.h>

#define SIZE 1024
#define NH 16
#define HD 64
#define BB 2
#define SS 2048
#define MROWS (BB * SS)  // 4096
#define QT 256           // attn q-tile (64 rows per wave)
#define NQT (SS / QT)    // 8 q-tiles per (b,h)
#define NKT ((SS / 2) / 64)  // 16 k-tiles per S-half

using bf16 = __hip_bfloat16;
using frag16 = __attribute__((ext_vector_type(8))) short;   // 8 bf16 (4 VGPRs)
using f32x4 = __attribute__((ext_vector_type(4))) float;    // 4 fp32 acc
typedef unsigned int u32;

// async global->LDS, 16B per lane; lds dest = wave-uniform base + lane*16 (m97/m104)
__device__ __forceinline__ void glds16(const bf16* g, bf16* l) {
    __builtin_amdgcn_global_load_lds(
        (const __attribute__((address_space(1))) u32*)g,
        (__attribute__((address_space(3))) u32*)l, 16, 0, 0);
}

__device__ __forceinline__ void cvt_store8(bf16* dst, const float* src) {
    float4 a = *(const float4*)src;
    float4 b = *(const float4*)(src + 4);
    bf16 t[8];
    t[0] = __float2bfloat16(a.x); t[1] = __float2bfloat16(a.y);
    t[2] = __float2bfloat16(a.z); t[3] = __float2bfloat16(a.w);
    t[4] = __float2bfloat16(b.x); t[5] = __float2bfloat16(b.y);
    t[6] = __float2bfloat16(b.z); t[7] = __float2bfloat16(b.w);
    *(uint4*)dst = *(const uint4*)t;
}

// ---------------------------------------------------------------------------
// fp32 -> bf16 cast, flat grid (R4 version): 16M elems / 8 per thread.
// Restored: bf16 activations make qkv's x8 A-re-read cheap (R5's fp32-direct
// A caused 200MB FETCH/dispatch -> HBM-bound qkv at 91us).
// ---------------------------------------------------------------------------
__global__ __launch_bounds__(256) void cast_kernel(
    const float* __restrict__ Wq, const float* __restrict__ Wk,
    const float* __restrict__ Wv, const float* __restrict__ Wo,
    const float* __restrict__ q, const float* __restrict__ k,
    const float* __restrict__ v,
    bf16* __restrict__ Wb, bf16* __restrict__ qb,
    bf16* __restrict__ kb, bf16* __restrict__ vb)
{
    const size_t WN = (size_t)SIZE * SIZE;          // 1<<20
    const size_t AN = (size_t)MROWS * SIZE;         // 1<<22
    const size_t e = ((size_t)blockIdx.x * 256 + threadIdx.x) * 8;
    if (e < 4 * WN) {
        const int which = (int)(e >> 20);
        const size_t off = e & (WN - 1);
        const float* s = (which == 0) ? Wq : (which == 1) ? Wk : (which == 2) ? Wv : Wo;
        cvt_store8(Wb + e, s + off);
    } else {
        const size_t a = e - 4 * WN;
        const int which = (int)(a >> 22);
        const size_t off = a & (AN - 1);
        const float* s = (which == 0) ? q : (which == 1) ? k : v;
        bf16* d = (which == 0) ? qb : (which == 1) ? kb : vb;
        cvt_store8(d + off, s + off);
    }
}

// ---------------------------------------------------------------------------
// qkv GEMM: 128x128 tile, BK=32, glds16 BOTH operands, DOUBLE-BUFFERED,
// ONE barrier per K-step (R3-attn-proven pipeline): glds16(kt+1 -> buf^1)
// issued BEFORE compute(buf); the trailing __syncthreads' vmcnt(0) drain now
// lands after the ~900-cyc MFMA phase instead of right after issue.
// (m151: glds16 beats reg-staging at 128^2 tiles, so both operands stay glds16.)
// vt_mode: epilogue transposes via LDS and writes vt[b][h][d][s] coalesced.
// ---------------------------------------------------------------------------
__device__ __forceinline__ void gemm_body(
    const bf16* __restrict__ X, const bf16* __restrict__ W,
    const float* __restrict__ bias, bf16* __restrict__ Y, float scale, bool vt_mode)
{
    __shared__ __align__(16) bf16 smem[16384];   // As[2][4096] | Bs[2][4096]; tr reuse
    bf16* As = smem;                             // buf b at As + b*4096
    bf16* Bs = smem + 8192;

    const int tid = threadIdx.x;
    const int wave = tid >> 6;
    const int lane = tid & 63;
    const int lane15 = lane & 15;
    const int quad = lane >> 4;
    const int bm = blockIdx.y * 128;
    const int bn = blockIdx.x * 128;
    const int wm = (wave & 1) * 64;
    const int wn = (wave >> 1) * 64;

    f32x4 acc[4][4];
#pragma unroll
    for (int i = 0; i < 4; i++)
#pragma unroll
        for (int j = 0; j < 4; j++)
            acc[i][j] = (f32x4){0.f, 0.f, 0.f, 0.f};

    const int srow = lane >> 2;        // 0..15 within 16-row chunk
    const int scol = (lane & 3) * 8;   // 0/8/16/24

#define STAGE(KT, BUF)                                                         \
    {                                                                          \
        _Pragma("unroll")                                                      \
        for (int n = 0; n < 2; n++) {                                          \
            const int c = wave * 2 + n;   /* chunk 0..7, 16 rows each */       \
            glds16(X + (size_t)(bm + c * 16 + srow) * SIZE + (KT) * 32 + scol, \
                   As + (BUF) * 4096 + c * 512);                               \
            glds16(W + (size_t)(bn + c * 16 + srow) * SIZE + (KT) * 32 + scol, \
                   Bs + (BUF) * 4096 + c * 512);                               \
        }                                                                      \
    }

    // prologue: tile 0 (latency exposed once)
    STAGE(0, 0);
    __syncthreads();

    for (int kt = 0; kt < SIZE / 32; kt++) {
        const int buf = kt & 1;
        if (kt + 1 < SIZE / 32) STAGE(kt + 1, buf ^ 1);   // prefetch -> other buffer
        __builtin_amdgcn_sched_barrier(0);                // pin prefetch before compute

        frag16 a[4], b[4];
#pragma unroll
        for (int mi = 0; mi < 4; mi++)
            a[mi] = *(const frag16*)(As + buf * 4096 + (wm + mi * 16 + lane15) * 32 + quad * 8);
#pragma unroll
        for (int ni = 0; ni < 4; ni++)
            b[ni] = *(const frag16*)(Bs + buf * 4096 + (wn + ni * 16 + lane15) * 32 + quad * 8);
#pragma unroll
        for (int mi = 0; mi < 4; mi++)
#pragma unroll
            for (int ni = 0; ni < 4; ni++)
                acc[mi][ni] = __builtin_amdgcn_mfma_f32_16x16x32_bf16(
                    a[mi], b[ni], acc[mi][ni], 0, 0, 0);

        __syncthreads();   // drains prefetch glds16 (vmcnt0) AFTER compute; buf^1 ready
    }
#undef STAGE

    if (!vt_mode) {
        // C/D layout col=lane&15, row=quad*4+reg (m89/m91)
#pragma unroll
        for (int ni = 0; ni < 4; ni++) {
            const int col = bn + wn + ni * 16 + lane15;
            const float bv = bias[col];
#pragma unroll
            for (int mi = 0; mi < 4; mi++) {
                const int row = bm + wm + mi * 16 + quad * 4;
#pragma unroll
                for (int r = 0; r < 4; r++)
                    Y[(size_t)(row + r) * SIZE + col] =
                        __float2bfloat16((acc[mi][ni][r] + bv) * scale);
            }
        }
    } else {
        // transpose epilogue -> vt[b][h][d][s], coalesced 16B stores
        bf16* tr = smem;                   // [64][136] = 8704 elems, fits
        const int bloc = bm >> 11;
        const int s0g = bm & (SS - 1);
#pragma unroll
        for (int p = 0; p < 2; p++) {
            __syncthreads();
            if ((wave >> 1) == p) {
#pragma unroll
                for (int ni = 0; ni < 4; ni++) {
                    const int colp = ni * 16 + lane15;
                    const float bv = bias[bn + p * 64 + colp];
#pragma unroll
                    for (int mi = 0; mi < 4; mi++) {
                        const int row = wm + mi * 16 + quad * 4;
#pragma unroll
                        for (int r = 0; r < 4; r++)
                            tr[colp * 136 + row + r] =
                                __float2bfloat16(acc[mi][ni][r] + bv);
                    }
                }
            }
            __syncthreads();
            const int colp = tid >> 2;
            const int gcol = bn + p * 64 + colp;
            const int hh = gcol >> 6, dd = gcol & (HD - 1);
            bf16* dst = (bf16*)Y + ((size_t)(bloc * NH + hh) * HD + dd) * SS
                        + s0g + (tid & 3) * 32;
            const bf16* src = tr + colp * 136 + (tid & 3) * 32;
#pragma unroll
            for (int j = 0; j < 4; j++)
                *(uint4*)(dst + j * 8) = *(const uint4*)(src + j * 8);
        }
    }
}

__global__ __launch_bounds__(256) void qkv_proj_kernel(
    const bf16* __restrict__ qb, const bf16* __restrict__ kb, const bf16* __restrict__ vb,
    const bf16* __restrict__ Wb,
    const float* __restrict__ bq, const float* __restrict__ bk, const float* __restrict__ bv,
    bf16* __restrict__ qh, bf16* __restrict__ kh, bf16* __restrict__ vt)
{
    const bf16 *X, *W; const float* bi; bf16* Y; float sc; bool vm;
    if (blockIdx.z == 0)      { X = qb; W = Wb;                   bi = bq; Y = qh; sc = 0.125f; vm = false; }
    else if (blockIdx.z == 1) { X = kb; W = Wb + SIZE * SIZE;     bi = bk; Y = kh; sc = 1.0f;   vm = false; }
    else                      { X = vb; W = Wb + 2 * SIZE * SIZE; bi = bv; Y = vt; sc = 1.0f;   vm = true;  }
    gemm_body(X, W, bi, Y, sc, vm);
}

// ---------------------------------------------------------------------------
// Flash attention, split-S, QT=256 (64 q-rows/wave), DOUBLE-BUFFERED K/V.
// (R3-proven: 66.6us. Frozen.)
// ---------------------------------------------------------------------------
__global__ __launch_bounds__(256) void attn_kernel(
    const bf16* __restrict__ qh, const bf16* __restrict__ kh,
    const bf16* __restrict__ vt, bf16* __restrict__ po, float* __restrict__ pl)
{
    __shared__ __align__(16) bf16 Ks[2][64][72];
    __shared__ __align__(16) bf16 Vs[2][64][72];
    __shared__ __align__(16) bf16 Ps[4][64][72];

    const int tid = threadIdx.x;
    const int wave = tid >> 6;
    const int lane = tid & 63;
    const int lane15 = lane & 15;
    const int quad = lane >> 4;

    const int b = blockIdx.z, h = blockIdx.y;
    const int qt = blockIdx.x >> 1;
    const int sh = blockIdx.x & 1;
    const int q0 = qt * QT;

    const size_t baseq = (size_t)b * SS * SIZE + (size_t)h * HD;
    const size_t basev = (size_t)(b * NH + h) * HD * SS;
    const float LOG2E = 1.44269504088896340736f;
    const float OFF = 12.0f * LOG2E;

    frag16 aq[4][2];
#pragma unroll
    for (int m = 0; m < 4; m++) {
        const int qrow = q0 + wave * 64 + m * 16 + lane15;
        const bf16* qp = qh + baseq + (size_t)qrow * SIZE + quad * 8;
        aq[m][0] = *(const frag16*)(qp);
        aq[m][1] = *(const frag16*)(qp + 32);
    }

    frag16 bones;
#pragma unroll
    for (int e = 0; e < 8; e++) bones[e] = (short)0x3F80;   // bf16 1.0

    f32x4 ofrag[4][4], l_frag[4];
#pragma unroll
    for (int m = 0; m < 4; m++) {
        l_frag[m] = (f32x4){0.f, 0.f, 0.f, 0.f};
#pragma unroll
        for (int dt = 0; dt < 4; dt++) ofrag[m][dt] = (f32x4){0.f, 0.f, 0.f, 0.f};
    }

    const int sr = tid >> 3;          // 0..31
    const int sc = (tid & 7) * 8;

    // staging registers (tile in flight)
    uint4 rk0, rk1, rv0, rv1;

#define ISSUE(KT)                                                              \
    {                                                                          \
        const int s0_ = sh * (SS / 2) + (KT) * 64;                             \
        rk0 = *(const uint4*)(kh + baseq + (size_t)(s0_ + sr) * SIZE + sc);    \
        rk1 = *(const uint4*)(kh + baseq + (size_t)(s0_ + sr + 32) * SIZE + sc);\
        rv0 = *(const uint4*)(vt + basev + (size_t)sr * SS + s0_ + sc);        \
        rv1 = *(const uint4*)(vt + basev + (size_t)(sr + 32) * SS + s0_ + sc); \
    }
#define COMMIT(BUF)                                                            \
    {                                                                          \
        *(uint4*)&Ks[BUF][sr][sc] = rk0; *(uint4*)&Ks[BUF][sr + 32][sc] = rk1; \
        *(uint4*)&Vs[BUF][sr][sc] = rv0; *(uint4*)&Vs[BUF][sr + 32][sc] = rv1; \
    }

    // prologue: tile 0 (latency exposed once)
    ISSUE(0); COMMIT(0);
    __syncthreads();

    for (int kt = 0; kt < NKT; kt++) {
        const int buf = kt & 1;
        if (kt + 1 < NKT) ISSUE(kt + 1);          // prefetch in flight
        __builtin_amdgcn_sched_barrier(0);        // pin loads before compute

        // ---- S^T = K Q^T, softmax, packed P store ----
        frag16 kf[4][2];
#pragma unroll
        for (int nt = 0; nt < 4; nt++) {
            kf[nt][0] = *(const frag16*)&Ks[buf][nt * 16 + lane15][quad * 8];
            kf[nt][1] = *(const frag16*)&Ks[buf][nt * 16 + lane15][32 + quad * 8];
        }
#pragma unroll
        for (int m = 0; m < 4; m++) {
#pragma unroll
            for (int nt = 0; nt < 4; nt++) {
                f32x4 c = (f32x4){0.f, 0.f, 0.f, 0.f};
                c = __builtin_amdgcn_mfma_f32_16x16x32_bf16(kf[nt][0], aq[m][0], c, 0, 0, 0);
                c = __builtin_amdgcn_mfma_f32_16x16x32_bf16(kf[nt][1], aq[m][1], c, 0, 0, 0);
                // c[r] = S[q = m*16+lane15][key = nt*16 + quad*4 + r]
                bf16 p4[4];
#pragma unroll
                for (int r = 0; r < 4; r++)
                    p4[r] = __float2bfloat16(exp2f(c[r] * LOG2E - OFF));
                *(uint2*)&Ps[wave][m * 16 + lane15][nt * 16 + quad * 4] = *(const uint2*)p4;
            }
        }
        __builtin_amdgcn_wave_barrier();   // Ps wave-private; DS in-order per wave

        frag16 ap[4][2];
#pragma unroll
        for (int m = 0; m < 4; m++)
#pragma unroll
            for (int c2 = 0; c2 < 2; c2++)
                ap[m][c2] = *(const frag16*)&Ps[wave][m * 16 + lane15][c2 * 32 + quad * 8];

        __builtin_amdgcn_s_setprio(1);
        // ---- l += P @ 1 ----
#pragma unroll
        for (int m = 0; m < 4; m++)
#pragma unroll
            for (int c2 = 0; c2 < 2; c2++)
                l_frag[m] = __builtin_amdgcn_mfma_f32_16x16x32_bf16(
                    ap[m][c2], bones, l_frag[m], 0, 0, 0);

        // ---- O += P V ----
#pragma unroll
        for (int dt = 0; dt < 4; dt++) {
            frag16 bv0 = *(const frag16*)&Vs[buf][dt * 16 + lane15][quad * 8];
            frag16 bv1 = *(const frag16*)&Vs[buf][dt * 16 + lane15][32 + quad * 8];
#pragma unroll
            for (int m = 0; m < 4; m++) {
                ofrag[m][dt] = __builtin_amdgcn_mfma_f32_16x16x32_bf16(ap[m][0], bv0, ofrag[m][dt], 0, 0, 0);
                ofrag[m][dt] = __builtin_amdgcn_mfma_f32_16x16x32_bf16(ap[m][1], bv1, ofrag[m][dt], 0, 0, 0);
            }
        }
        __builtin_amdgcn_s_setprio(0);

        if (kt + 1 < NKT) {
            COMMIT(buf ^ 1);                      // prefetch landed by now
            __syncthreads();
        }
    }
#undef ISSUE
#undef COMMIT

    // ---- partial outputs (un-normalized O + row sums) ----
    const int pb = ((b * NH + h) * NQT + qt) * 2 + sh;
    if (lane15 == 0) {
        float* plp = pl + (size_t)pb * QT;
#pragma unroll
        for (int m = 0; m < 4; m++)
#pragma unroll
            for (int r = 0; r < 4; r++)
                plp[wave * 64 + m * 16 + quad * 4 + r] = l_frag[m][r];
    }
    bf16* pop = po + (size_t)pb * QT * HD;
#pragma unroll
    for (int m = 0; m < 4; m++)
#pragma unroll
        for (int dt = 0; dt < 4; dt++)
#pragma unroll
            for (int r = 0; r < 4; r++)
                pop[(size_t)(wave * 64 + m * 16 + quad * 4 + r) * HD + dt * 16 + lane15] =
                    __float2bfloat16(ofrag[m][dt][r]);
}

// ---------------------------------------------------------------------------
// Output projection with FUSED combine (R4 structure, frozen): A-tile =
// (po0+po1)*inv in registers, B = Wo via glds16. BM=64 x BN=128, BK=64.
// ---------------------------------------------------------------------------
__global__ __launch_bounds__(256) void out_proj_kernel(
    const bf16* __restrict__ po, const float* __restrict__ pl,
    const bf16* __restrict__ Wob, const float* __restrict__ bo,
    float* __restrict__ out)
{
    __shared__ __align__(16) bf16 As[2 * 64 * 32];    // [2 planes][64][32]
    __shared__ __align__(16) bf16 Bs[2 * 128 * 32];   // [2 planes][128][32]

    const int tid = threadIdx.x;
    const int wave = tid >> 6;
    const int lane = tid & 63;
    const int lane15 = lane & 15;
    const int quad = lane >> 4;
    const int bm = blockIdx.y * 64;
    const int bn = blockIdx.x * 128;
    const int wn = wave * 32;

    f32x4 acc[4][2];
#pragma unroll
    for (int i = 0; i < 4; i++)
#pragma unroll
        for (int j = 0; j < 2; j++)
            acc[i][j] = (f32x4){0.f, 0.f, 0.f, 0.f};

    const int srow = lane >> 2;        // 0..15
    const int scol = (lane & 3) * 8;

    const int arow = tid >> 2;
    const int acol = (tid & 3) * 8;
    const int gr = bm + arow;                 // global ctx row
    const int bIdx = gr >> 11;                // batch
    const int s = gr & (SS - 1);
    const int qt8 = s >> 8;                   // 256-row attn tile
    const int sq = s & (QT - 1);

    uint4 p0a, p1a, p0b, p1b;                 // {half0,half1} x {plane0,plane1}
    float l0, l1;

#define ALOAD(KT)                                                                 \
    {                                                                             \
        const int pb0_ = ((bIdx * NH + (KT)) * NQT + qt8) * 2;                    \
        const bf16* q0_ = po + (size_t)pb0_ * QT * HD + sq * HD;                  \
        const bf16* q1_ = po + (size_t)(pb0_ + 1) * QT * HD + sq * HD;            \
        p0a = *(const uint4*)(q0_ + acol);                                        \
        p0b = *(const uint4*)(q0_ + 32 + acol);                                   \
        p1a = *(const uint4*)(q1_ + acol);                                        \
        p1b = *(const uint4*)(q1_ + 32 + acol);                                   \
        l0 = pl[(size_t)pb0_ * QT + sq];                                          \
        l1 = pl[(size_t)(pb0_ + 1) * QT + sq];                                    \
    }

    ALOAD(0);

    for (int kt = 0; kt < NH; kt++) {         // 16 iterations, k0 = kt*64, h = kt
        __syncthreads();                      // prev readers done
        // ---- commit A (fused combine) ----
        {
            const float inv = 1.0f / fmaxf(l0 + l1, 1e-30f);
            const bf16* x0 = (const bf16*)&p0a; const bf16* y0 = (const bf16*)&p1a;
            const bf16* x1 = (const bf16*)&p0b; const bf16* y1 = (const bf16*)&p1b;
            bf16 o0[8], o1[8];
#pragma unroll
            for (int e = 0; e < 8; e++) {
                o0[e] = __float2bfloat16((__bfloat162float(x0[e]) + __bfloat162float(y0[e])) * inv);
                o1[e] = __float2bfloat16((__bfloat162float(x1[e]) + __bfloat162float(y1[e])) * inv);
            }
            *(uint4*)(As + 0 * 2048 + arow * 32 + acol) = *(const uint4*)o0;
            *(uint4*)(As + 1 * 2048 + arow * 32 + acol) = *(const uint4*)o1;
        }
        // ---- B glds16 staging ----
#pragma unroll
        for (int n = 0; n < 4; n++) {
            const int c = wave * 4 + n;
            const int plane = c >> 3;
            const int cc = c & 7;
            glds16(Wob + (size_t)(bn + cc * 16 + srow) * SIZE + kt * 64 + plane * 32 + scol,
                   Bs + c * 512);
        }
        __syncthreads();                      // drain ds_write + glds16

        if (kt + 1 < NH) ALOAD(kt + 1);       // prefetch flows under MFMAs

#pragma unroll
        for (int kk = 0; kk < 2; kk++) {
            frag16 a[4], b[2];
#pragma unroll
            for (int mi = 0; mi < 4; mi++)
                a[mi] = *(const frag16*)(As + kk * 2048 + (mi * 16 + lane15) * 32 + quad * 8);
#pragma unroll
            for (int ni = 0; ni < 2; ni++)
                b[ni] = *(const frag16*)(Bs + kk * 4096 + (wn + ni * 16 + lane15) * 32 + quad * 8);
#pragma unroll
            for (int mi = 0; mi < 4; mi++)
#pragma unroll
                for (int ni = 0; ni < 2; ni++)
                    acc[mi][ni] = __builtin_amdgcn_mfma_f32_16x16x32_bf16(
                        a[mi], b[ni], acc[mi][ni], 0, 0, 0);
        }
    }
#undef ALOAD

#pragma unroll
    for (int ni = 0; ni < 2; ni++) {
        const int col = bn + wn + ni * 16 + lane15;
        const float bv = bo[col];
#pragma unroll
        for (int mi = 0; mi < 4; mi++) {
            const int row = bm + mi * 16 + quad * 4;
#pragma unroll
            for (int r = 0; r < 4; r++)
                out[(size_t)(row + r) * SIZE + col] = acc[mi][ni][r] + bv;
        }
    }
}

extern "C" void kernel_launch(void* const* d_in, const int* in_sizes, int n_in,
                              void* d_out, int out_size, void* d_ws, size_t ws_size,
                              hipStream_t stream) {
    const float* q  = (const float*)d_in[0];
    const float* k  = (const float*)d_in[1];
    const float* v  = (const float*)d_in[2];
    const float* Wq = (const float*)d_in[3];
    const float* bq = (const float*)d_in[4];
    const float* Wk = (const float*)d_in[5];
    const float* bk = (const float*)d_in[6];
    const float* Wv = (const float*)d_in[7];
    const float* bv = (const float*)d_in[8];
    const float* Wo = (const float*)d_in[9];
    const float* bo = (const float*)d_in[10];
    float* out = (float*)d_out;

    // ws (bf16): Wb[4M] | qb | kb | vb | qh | kh | vt  (4.19M elems each)
    // aliases: po (8.39M) = qb+kb (dead after qkv); pl = Wq slot (dead after qkv)
    bf16* Wb  = (bf16*)d_ws;
    bf16* qb  = Wb + (size_t)4 * SIZE * SIZE;
    bf16* kb  = qb + (size_t)MROWS * SIZE;
    bf16* vb  = kb + (size_t)MROWS * SIZE;
    bf16* qh  = vb + (size_t)MROWS * SIZE;
    bf16* kh  = qh + (size_t)MROWS * SIZE;
    bf16* vt  = kh + (size_t)MROWS * SIZE;
    bf16* po  = qb;
    float* pl = (float*)Wb;

    cast_kernel<<<dim3(8192, 1, 1), 256, 0, stream>>>(
        Wq, Wk, Wv, Wo, q, k, v, Wb, qb, kb, vb);
    qkv_proj_kernel<<<dim3(SIZE / 128, MROWS / 128, 3), 256, 0, stream>>>(
        qb, kb, vb, Wb, bq, bk, bv, qh, kh, vt);
    attn_kernel<<<dim3(NQT * 2, NH, BB), 256, 0, stream>>>(qh, kh, vt, po, pl);
    out_proj_kernel<<<dim3(SIZE / 128, MROWS / 64, 1), 256, 0, stream>>>(
        po, pl, Wb + (size_t)3 * SIZE * SIZE, bo, out);
}

// Round 7
// 248.950 us; speedup vs baseline: 1.1177x; 1.0187x over previous
//
#include <hip/hip_runtime.h>
#include <hip/hip_bf16.h>

#define SIZE 1024
#define NH 16
#define HD 64
#define BB 2
#define SS 2048
#define MROWS (BB * SS)  // 4096
#define QT 256           // attn q-tile (64 rows per wave)
#define NQT (SS / QT)    // 8 q-tiles per (b,h)
#define NKT ((SS / 2) / 64)  // 16 k-tiles per S-half

using bf16 = __hip_bfloat16;
using frag16 = __attribute__((ext_vector_type(8))) short;   // 8 bf16 (4 VGPRs)
using f32x4 = __attribute__((ext_vector_type(4))) float;    // 4 fp32 acc
typedef unsigned int u32;

// async global->LDS, 16B per lane; lds dest = wave-uniform base + lane*16 (m97/m104)
__device__ __forceinline__ void glds16(const bf16* g, bf16* l) {
    __builtin_amdgcn_global_load_lds(
        (const __attribute__((address_space(1))) u32*)g,
        (__attribute__((address_space(3))) u32*)l, 16, 0, 0);
}

__device__ __forceinline__ void cvt_store8(bf16* dst, const float* src) {
    float4 a = *(const float4*)src;
    float4 b = *(const float4*)(src + 4);
    bf16 t[8];
    t[0] = __float2bfloat16(a.x); t[1] = __float2bfloat16(a.y);
    t[2] = __float2bfloat16(a.z); t[3] = __float2bfloat16(a.w);
    t[4] = __float2bfloat16(b.x); t[5] = __float2bfloat16(b.y);
    t[6] = __float2bfloat16(b.z); t[7] = __float2bfloat16(b.w);
    *(uint4*)dst = *(const uint4*)t;
}

// ---------------------------------------------------------------------------
// fp32 -> bf16 cast, flat grid: 16M elems / 8 per thread.
// ---------------------------------------------------------------------------
__global__ __launch_bounds__(256) void cast_kernel(
    const float* __restrict__ Wq, const float* __restrict__ Wk,
    const float* __restrict__ Wv, const float* __restrict__ Wo,
    const float* __restrict__ q, const float* __restrict__ k,
    const float* __restrict__ v,
    bf16* __restrict__ Wb, bf16* __restrict__ qb,
    bf16* __restrict__ kb, bf16* __restrict__ vb)
{
    const size_t WN = (size_t)SIZE * SIZE;          // 1<<20
    const size_t AN = (size_t)MROWS * SIZE;         // 1<<22
    const size_t e = ((size_t)blockIdx.x * 256 + threadIdx.x) * 8;
    if (e < 4 * WN) {
        const int which = (int)(e >> 20);
        const size_t off = e & (WN - 1);
        const float* s = (which == 0) ? Wq : (which == 1) ? Wk : (which == 2) ? Wv : Wo;
        cvt_store8(Wb + e, s + off);
    } else {
        const size_t a = e - 4 * WN;
        const int which = (int)(a >> 22);
        const size_t off = a & (AN - 1);
        const float* s = (which == 0) ? q : (which == 1) ? k : v;
        bf16* d = (which == 0) ? qb : (which == 1) ? kb : vb;
        cvt_store8(d + off, s + off);
    }
}

// ---------------------------------------------------------------------------
// qkv GEMM: 128x128 tile, BK=32, glds16 BOTH operands, DOUBLE-BUFFERED,
// ONE barrier per K-step (R6 structure). NOW XCD-SWIZZLED (T1): caller
// passes bm/bn decoded from a bijective chunk map so each XCD owns a
// contiguous run of x-fastest work -> A-panels fetched once per XCD, W
// slice stays L2-resident (fixes the x8 cross-XCD A-re-fetch).
// vt_mode: epilogue transposes via LDS and writes vt[b][h][d][s] coalesced.
// ---------------------------------------------------------------------------
__device__ __forceinline__ void gemm_body(
    const bf16* __restrict__ X, const bf16* __restrict__ W,
    const float* __restrict__ bias, bf16* __restrict__ Y, float scale, bool vt_mode,
    int bm, int bn)
{
    __shared__ __align__(16) bf16 smem[16384];   // As[2][4096] | Bs[2][4096]; tr reuse
    bf16* As = smem;                             // buf b at As + b*4096
    bf16* Bs = smem + 8192;

    const int tid = threadIdx.x;
    const int wave = tid >> 6;
    const int lane = tid & 63;
    const int lane15 = lane & 15;
    const int quad = lane >> 4;
    const int wm = (wave & 1) * 64;
    const int wn = (wave >> 1) * 64;

    f32x4 acc[4][4];
#pragma unroll
    for (int i = 0; i < 4; i++)
#pragma unroll
        for (int j = 0; j < 4; j++)
            acc[i][j] = (f32x4){0.f, 0.f, 0.f, 0.f};

    const int srow = lane >> 2;        // 0..15 within 16-row chunk
    const int scol = (lane & 3) * 8;   // 0/8/16/24

#define STAGE(KT, BUF)                                                         \
    {                                                                          \
        _Pragma("unroll")                                                      \
        for (int n = 0; n < 2; n++) {                                          \
            const int c = wave * 2 + n;   /* chunk 0..7, 16 rows each */       \
            glds16(X + (size_t)(bm + c * 16 + srow) * SIZE + (KT) * 32 + scol, \
                   As + (BUF) * 4096 + c * 512);                               \
            glds16(W + (size_t)(bn + c * 16 + srow) * SIZE + (KT) * 32 + scol, \
                   Bs + (BUF) * 4096 + c * 512);                               \
        }                                                                      \
    }

    // prologue: tile 0 (latency exposed once)
    STAGE(0, 0);
    __syncthreads();

    for (int kt = 0; kt < SIZE / 32; kt++) {
        const int buf = kt & 1;
        if (kt + 1 < SIZE / 32) STAGE(kt + 1, buf ^ 1);   // prefetch -> other buffer
        __builtin_amdgcn_sched_barrier(0);                // pin prefetch before compute

        frag16 a[4], b[4];
#pragma unroll
        for (int mi = 0; mi < 4; mi++)
            a[mi] = *(const frag16*)(As + buf * 4096 + (wm + mi * 16 + lane15) * 32 + quad * 8);
#pragma unroll
        for (int ni = 0; ni < 4; ni++)
            b[ni] = *(const frag16*)(Bs + buf * 4096 + (wn + ni * 16 + lane15) * 32 + quad * 8);
#pragma unroll
        for (int mi = 0; mi < 4; mi++)
#pragma unroll
            for (int ni = 0; ni < 4; ni++)
                acc[mi][ni] = __builtin_amdgcn_mfma_f32_16x16x32_bf16(
                    a[mi], b[ni], acc[mi][ni], 0, 0, 0);

        __syncthreads();   // drains prefetch glds16 (vmcnt0) AFTER compute; buf^1 ready
    }
#undef STAGE

    if (!vt_mode) {
        // C/D layout col=lane&15, row=quad*4+reg (m89/m91)
#pragma unroll
        for (int ni = 0; ni < 4; ni++) {
            const int col = bn + wn + ni * 16 + lane15;
            const float bv = bias[col];
#pragma unroll
            for (int mi = 0; mi < 4; mi++) {
                const int row = bm + wm + mi * 16 + quad * 4;
#pragma unroll
                for (int r = 0; r < 4; r++)
                    Y[(size_t)(row + r) * SIZE + col] =
                        __float2bfloat16((acc[mi][ni][r] + bv) * scale);
            }
        }
    } else {
        // transpose epilogue -> vt[b][h][d][s], coalesced 16B stores
        bf16* tr = smem;                   // [64][136] = 8704 elems, fits
        const int bloc = bm >> 11;
        const int s0g = bm & (SS - 1);
#pragma unroll
        for (int p = 0; p < 2; p++) {
            __syncthreads();
            if ((wave >> 1) == p) {
#pragma unroll
                for (int ni = 0; ni < 4; ni++) {
                    const int colp = ni * 16 + lane15;
                    const float bv = bias[bn + p * 64 + colp];
#pragma unroll
                    for (int mi = 0; mi < 4; mi++) {
                        const int row = wm + mi * 16 + quad * 4;
#pragma unroll
                        for (int r = 0; r < 4; r++)
                            tr[colp * 136 + row + r] =
                                __float2bfloat16(acc[mi][ni][r] + bv);
                    }
                }
            }
            __syncthreads();
            const int colp = tid >> 2;
            const int gcol = bn + p * 64 + colp;
            const int hh = gcol >> 6, dd = gcol & (HD - 1);
            bf16* dst = (bf16*)Y + ((size_t)(bloc * NH + hh) * HD + dd) * SS
                        + s0g + (tid & 3) * 32;
            const bf16* src = tr + colp * 136 + (tid & 3) * 32;
#pragma unroll
            for (int j = 0; j < 4; j++)
                *(uint4*)(dst + j * 8) = *(const uint4*)(src + j * 8);
        }
    }
}

// 1-D grid of 768; bijective XCD swizzle (nwg=768, 768%8==0, chunk=96):
// work w = (f%8)*96 + f/8; decode x-fastest (8 col-tiles, 32 row-tiles, 3 z)
__global__ __launch_bounds__(256) void qkv_proj_kernel(
    const bf16* __restrict__ qb, const bf16* __restrict__ kb, const bf16* __restrict__ vb,
    const bf16* __restrict__ Wb,
    const float* __restrict__ bq, const float* __restrict__ bk, const float* __restrict__ bv,
    bf16* __restrict__ qh, bf16* __restrict__ kh, bf16* __restrict__ vt)
{
    const int f = blockIdx.x;
    const int w = (f & 7) * 96 + (f >> 3);
    const int z = w >> 8;             // /256 (blocks per z-slice)
    const int rem = w & 255;
    const int bn = (rem & 7) * 128;   // col tile (x-fastest within chunk)
    const int bm = (rem >> 3) * 128;  // row tile

    const bf16 *X, *W; const float* bi; bf16* Y; float sc; bool vm;
    if (z == 0)      { X = qb; W = Wb;                   bi = bq; Y = qh; sc = 0.125f; vm = false; }
    else if (z == 1) { X = kb; W = Wb + SIZE * SIZE;     bi = bk; Y = kh; sc = 1.0f;   vm = false; }
    else             { X = vb; W = Wb + 2 * SIZE * SIZE; bi = bv; Y = vt; sc = 1.0f;   vm = true;  }
    gemm_body(X, W, bi, Y, sc, vm, bm, bn);
}

// ---------------------------------------------------------------------------
// Flash attention, split-S, QT=256 (64 q-rows/wave), DOUBLE-BUFFERED K/V.
// (R3-proven: 66.6us. Frozen.)
// ---------------------------------------------------------------------------
__global__ __launch_bounds__(256) void attn_kernel(
    const bf16* __restrict__ qh, const bf16* __restrict__ kh,
    const bf16* __restrict__ vt, bf16* __restrict__ po, float* __restrict__ pl)
{
    __shared__ __align__(16) bf16 Ks[2][64][72];
    __shared__ __align__(16) bf16 Vs[2][64][72];
    __shared__ __align__(16) bf16 Ps[4][64][72];

    const int tid = threadIdx.x;
    const int wave = tid >> 6;
    const int lane = tid & 63;
    const int lane15 = lane & 15;
    const int quad = lane >> 4;

    const int b = blockIdx.z, h = blockIdx.y;
    const int qt = blockIdx.x >> 1;
    const int sh = blockIdx.x & 1;
    const int q0 = qt * QT;

    const size_t baseq = (size_t)b * SS * SIZE + (size_t)h * HD;
    const size_t basev = (size_t)(b * NH + h) * HD * SS;
    const float LOG2E = 1.44269504088896340736f;
    const float OFF = 12.0f * LOG2E;

    frag16 aq[4][2];
#pragma unroll
    for (int m = 0; m < 4; m++) {
        const int qrow = q0 + wave * 64 + m * 16 + lane15;
        const bf16* qp = qh + baseq + (size_t)qrow * SIZE + quad * 8;
        aq[m][0] = *(const frag16*)(qp);
        aq[m][1] = *(const frag16*)(qp + 32);
    }

    frag16 bones;
#pragma unroll
    for (int e = 0; e < 8; e++) bones[e] = (short)0x3F80;   // bf16 1.0

    f32x4 ofrag[4][4], l_frag[4];
#pragma unroll
    for (int m = 0; m < 4; m++) {
        l_frag[m] = (f32x4){0.f, 0.f, 0.f, 0.f};
#pragma unroll
        for (int dt = 0; dt < 4; dt++) ofrag[m][dt] = (f32x4){0.f, 0.f, 0.f, 0.f};
    }

    const int sr = tid >> 3;          // 0..31
    const int sc = (tid & 7) * 8;

    // staging registers (tile in flight)
    uint4 rk0, rk1, rv0, rv1;

#define ISSUE(KT)                                                              \
    {                                                                          \
        const int s0_ = sh * (SS / 2) + (KT) * 64;                             \
        rk0 = *(const uint4*)(kh + baseq + (size_t)(s0_ + sr) * SIZE + sc);    \
        rk1 = *(const uint4*)(kh + baseq + (size_t)(s0_ + sr + 32) * SIZE + sc);\
        rv0 = *(const uint4*)(vt + basev + (size_t)sr * SS + s0_ + sc);        \
        rv1 = *(const uint4*)(vt + basev + (size_t)(sr + 32) * SS + s0_ + sc); \
    }
#define COMMIT(BUF)                                                            \
    {                                                                          \
        *(uint4*)&Ks[BUF][sr][sc] = rk0; *(uint4*)&Ks[BUF][sr + 32][sc] = rk1; \
        *(uint4*)&Vs[BUF][sr][sc] = rv0; *(uint4*)&Vs[BUF][sr + 32][sc] = rv1; \
    }

    // prologue: tile 0 (latency exposed once)
    ISSUE(0); COMMIT(0);
    __syncthreads();

    for (int kt = 0; kt < NKT; kt++) {
        const int buf = kt & 1;
        if (kt + 1 < NKT) ISSUE(kt + 1);          // prefetch in flight
        __builtin_amdgcn_sched_barrier(0);        // pin loads before compute

        // ---- S^T = K Q^T, softmax, packed P store ----
        frag16 kf[4][2];
#pragma unroll
        for (int nt = 0; nt < 4; nt++) {
            kf[nt][0] = *(const frag16*)&Ks[buf][nt * 16 + lane15][quad * 8];
            kf[nt][1] = *(const frag16*)&Ks[buf][nt * 16 + lane15][32 + quad * 8];
        }
#pragma unroll
        for (int m = 0; m < 4; m++) {
#pragma unroll
            for (int nt = 0; nt < 4; nt++) {
                f32x4 c = (f32x4){0.f, 0.f, 0.f, 0.f};
                c = __builtin_amdgcn_mfma_f32_16x16x32_bf16(kf[nt][0], aq[m][0], c, 0, 0, 0);
                c = __builtin_amdgcn_mfma_f32_16x16x32_bf16(kf[nt][1], aq[m][1], c, 0, 0, 0);
                // c[r] = S[q = m*16+lane15][key = nt*16 + quad*4 + r]
                bf16 p4[4];
#pragma unroll
                for (int r = 0; r < 4; r++)
                    p4[r] = __float2bfloat16(exp2f(c[r] * LOG2E - OFF));
                *(uint2*)&Ps[wave][m * 16 + lane15][nt * 16 + quad * 4] = *(const uint2*)p4;
            }
        }
        __builtin_amdgcn_wave_barrier();   // Ps wave-private; DS in-order per wave

        frag16 ap[4][2];
#pragma unroll
        for (int m = 0; m < 4; m++)
#pragma unroll
            for (int c2 = 0; c2 < 2; c2++)
                ap[m][c2] = *(const frag16*)&Ps[wave][m * 16 + lane15][c2 * 32 + quad * 8];

        __builtin_amdgcn_s_setprio(1);
        // ---- l += P @ 1 ----
#pragma unroll
        for (int m = 0; m < 4; m++)
#pragma unroll
            for (int c2 = 0; c2 < 2; c2++)
                l_frag[m] = __builtin_amdgcn_mfma_f32_16x16x32_bf16(
                    ap[m][c2], bones, l_frag[m], 0, 0, 0);

        // ---- O += P V ----
#pragma unroll
        for (int dt = 0; dt < 4; dt++) {
            frag16 bv0 = *(const frag16*)&Vs[buf][dt * 16 + lane15][quad * 8];
            frag16 bv1 = *(const frag16*)&Vs[buf][dt * 16 + lane15][32 + quad * 8];
#pragma unroll
            for (int m = 0; m < 4; m++) {
                ofrag[m][dt] = __builtin_amdgcn_mfma_f32_16x16x32_bf16(ap[m][0], bv0, ofrag[m][dt], 0, 0, 0);
                ofrag[m][dt] = __builtin_amdgcn_mfma_f32_16x16x32_bf16(ap[m][1], bv1, ofrag[m][dt], 0, 0, 0);
            }
        }
        __builtin_amdgcn_s_setprio(0);

        if (kt + 1 < NKT) {
            COMMIT(buf ^ 1);                      // prefetch landed by now
            __syncthreads();
        }
    }
#undef ISSUE
#undef COMMIT

    // ---- partial outputs (un-normalized O + row sums) ----
    const int pb = ((b * NH + h) * NQT + qt) * 2 + sh;
    if (lane15 == 0) {
        float* plp = pl + (size_t)pb * QT;
#pragma unroll
        for (int m = 0; m < 4; m++)
#pragma unroll
            for (int r = 0; r < 4; r++)
                plp[wave * 64 + m * 16 + quad * 4 + r] = l_frag[m][r];
    }
    bf16* pop = po + (size_t)pb * QT * HD;
#pragma unroll
    for (int m = 0; m < 4; m++)
#pragma unroll
        for (int dt = 0; dt < 4; dt++)
#pragma unroll
            for (int r = 0; r < 4; r++)
                pop[(size_t)(wave * 64 + m * 16 + quad * 4 + r) * HD + dt * 16 + lane15] =
                    __float2bfloat16(ofrag[m][dt][r]);
}

// ---------------------------------------------------------------------------
// Output projection with FUSED combine (R4 structure), NOW XCD-SWIZZLED:
// 1-D grid 512, chunk=64 -> each XCD owns 8 row-panels x all 8 col-tiles;
// po-panels fetched once per XCD, Wo stays L2-resident.
// ---------------------------------------------------------------------------
__global__ __launch_bounds__(256) void out_proj_kernel(
    const bf16* __restrict__ po, const float* __restrict__ pl,
    const bf16* __restrict__ Wob, const float* __restrict__ bo,
    float* __restrict__ out)
{
    __shared__ __align__(16) bf16 As[2 * 64 * 32];    // [2 planes][64][32]
    __shared__ __align__(16) bf16 Bs[2 * 128 * 32];   // [2 planes][128][32]

    const int f = blockIdx.x;
    const int w = (f & 7) * 64 + (f >> 3);    // bijective, nwg=512
    const int bn = (w & 7) * 128;             // col tile (x-fastest)
    const int bm = (w >> 3) * 64;             // row tile

    const int tid = threadIdx.x;
    const int wave = tid >> 6;
    const int lane = tid & 63;
    const int lane15 = lane & 15;
    const int quad = lane >> 4;
    const int wn = wave * 32;

    f32x4 acc[4][2];
#pragma unroll
    for (int i = 0; i < 4; i++)
#pragma unroll
        for (int j = 0; j < 2; j++)
            acc[i][j] = (f32x4){0.f, 0.f, 0.f, 0.f};

    const int srow = lane >> 2;        // 0..15
    const int scol = (lane & 3) * 8;

    const int arow = tid >> 2;
    const int acol = (tid & 3) * 8;
    const int gr = bm + arow;                 // global ctx row
    const int bIdx = gr >> 11;                // batch
    const int s = gr & (SS - 1);
    const int qt8 = s >> 8;                   // 256-row attn tile
    const int sq = s & (QT - 1);

    uint4 p0a, p1a, p0b, p1b;                 // {half0,half1} x {plane0,plane1}
    float l0, l1;

#define ALOAD(KT)                                                                 \
    {                                                                             \
        const int pb0_ = ((bIdx * NH + (KT)) * NQT + qt8) * 2;                    \
        const bf16* q0_ = po + (size_t)pb0_ * QT * HD + sq * HD;                  \
        const bf16* q1_ = po + (size_t)(pb0_ + 1) * QT * HD + sq * HD;            \
        p0a = *(const uint4*)(q0_ + acol);                                        \
        p0b = *(const uint4*)(q0_ + 32 + acol);                                   \
        p1a = *(const uint4*)(q1_ + acol);                                        \
        p1b = *(const uint4*)(q1_ + 32 + acol);                                   \
        l0 = pl[(size_t)pb0_ * QT + sq];                                          \
        l1 = pl[(size_t)(pb0_ + 1) * QT + sq];                                    \
    }

    ALOAD(0);

    for (int kt = 0; kt < NH; kt++) {         // 16 iterations, k0 = kt*64, h = kt
        __syncthreads();                      // prev readers done
        // ---- commit A (fused combine) ----
        {
            const float inv = 1.0f / fmaxf(l0 + l1, 1e-30f);
            const bf16* x0 = (const bf16*)&p0a; const bf16* y0 = (const bf16*)&p1a;
            const bf16* x1 = (const bf16*)&p0b; const bf16* y1 = (const bf16*)&p1b;
            bf16 o0[8], o1[8];
#pragma unroll
            for (int e = 0; e < 8; e++) {
                o0[e] = __float2bfloat16((__bfloat162float(x0[e]) + __bfloat162float(y0[e])) * inv);
                o1[e] = __float2bfloat16((__bfloat162float(x1[e]) + __bfloat162float(y1[e])) * inv);
            }
            *(uint4*)(As + 0 * 2048 + arow * 32 + acol) = *(const uint4*)o0;
            *(uint4*)(As + 1 * 2048 + arow * 32 + acol) = *(const uint4*)o1;
        }
        // ---- B glds16 staging ----
#pragma unroll
        for (int n = 0; n < 4; n++) {
            const int c = wave * 4 + n;
            const int plane = c >> 3;
            const int cc = c & 7;
            glds16(Wob + (size_t)(bn + cc * 16 + srow) * SIZE + kt * 64 + plane * 32 + scol,
                   Bs + c * 512);
        }
        __syncthreads();                      // drain ds_write + glds16

        if (kt + 1 < NH) ALOAD(kt + 1);       // prefetch flows under MFMAs

#pragma unroll
        for (int kk = 0; kk < 2; kk++) {
            frag16 a[4], b[2];
#pragma unroll
            for (int mi = 0; mi < 4; mi++)
                a[mi] = *(const frag16*)(As + kk * 2048 + (mi * 16 + lane15) * 32 + quad * 8);
#pragma unroll
            for (int ni = 0; ni < 2; ni++)
                b[ni] = *(const frag16*)(Bs + kk * 4096 + (wn + ni * 16 + lane15) * 32 + quad * 8);
#pragma unroll
            for (int mi = 0; mi < 4; mi++)
#pragma unroll
                for (int ni = 0; ni < 2; ni++)
                    acc[mi][ni] = __builtin_amdgcn_mfma_f32_16x16x32_bf16(
                        a[mi], b[ni], acc[mi][ni], 0, 0, 0);
        }
    }
#undef ALOAD

#pragma unroll
    for (int ni = 0; ni < 2; ni++) {
        const int col = bn + wn + ni * 16 + lane15;
        const float bv = bo[col];
#pragma unroll
        for (int mi = 0; mi < 4; mi++) {
            const int row = bm + mi * 16 + quad * 4;
#pragma unroll
            for (int r = 0; r < 4; r++)
                out[(size_t)(row + r) * SIZE + col] = acc[mi][ni][r] + bv;
        }
    }
}

extern "C" void kernel_launch(void* const* d_in, const int* in_sizes, int n_in,
                              void* d_out, int out_size, void* d_ws, size_t ws_size,
                              hipStream_t stream) {
    const float* q  = (const float*)d_in[0];
    const float* k  = (const float*)d_in[1];
    const float* v  = (const float*)d_in[2];
    const float* Wq = (const float*)d_in[3];
    const float* bq = (const float*)d_in[4];
    const float* Wk = (const float*)d_in[5];
    const float* bk = (const float*)d_in[6];
    const float* Wv = (const float*)d_in[7];
    const float* bv = (const float*)d_in[8];
    const float* Wo = (const float*)d_in[9];
    const float* bo = (const float*)d_in[10];
    float* out = (float*)d_out;

    // ws (bf16): Wb[4M] | qb | kb | vb | qh | kh | vt  (4.19M elems each)
    // aliases: po (8.39M) = qb+kb (dead after qkv); pl = Wq slot (dead after qkv)
    bf16* Wb  = (bf16*)d_ws;
    bf16* qb  = Wb + (size_t)4 * SIZE * SIZE;
    bf16* kb  = qb + (size_t)MROWS * SIZE;
    bf16* vb  = kb + (size_t)MROWS * SIZE;
    bf16* qh  = vb + (size_t)MROWS * SIZE;
    bf16* kh  = qh + (size_t)MROWS * SIZE;
    bf16* vt  = kh + (size_t)MROWS * SIZE;
    bf16* po  = qb;
    float* pl = (float*)Wb;

    cast_kernel<<<dim3(8192, 1, 1), 256, 0, stream>>>(
        Wq, Wk, Wv, Wo, q, k, v, Wb, qb, kb, vb);
    qkv_proj_kernel<<<dim3(768, 1, 1), 256, 0, stream>>>(
        qb, kb, vb, Wb, bq, bk, bv, qh, kh, vt);
    attn_kernel<<<dim3(NQT * 2, NH, BB), 256, 0, stream>>>(qh, kh, vt, po, pl);
    out_proj_kernel<<<dim3(512, 1, 1), 256, 0, stream>>>(
        po, pl, Wb + (size_t)3 * SIZE * SIZE, bo, out);
}